// Round 1
// baseline (6561.382 us; speedup 1.0000x reference)
//
#include <hip/hip_runtime.h>
#include <hip/hip_bf16.h>

#define C_DIM 256
#define HW_DIM 16384
#define M_TOT 131072   // B*H*W = 8*128*128
#define F_DIM 1024

typedef __hip_bfloat16 bf16;

__device__ __forceinline__ float bf2f(bf16 v) { return __bfloat162float(v); }
__device__ __forceinline__ bf16 f2bf(float v) { return __float2bfloat16(v); }

// ---------------- kernel 0: weight transposes ----------------
// WTqkv [256 k][320 r], W1T [256 k][1024 f], W2T [1024 f][256 c]
__global__ __launch_bounds__(256) void prep_weights(
    const float* __restrict__ Wq, const float* __restrict__ Wk,
    const float* __restrict__ Wv, const float* __restrict__ W1,
    const float* __restrict__ W2, float* __restrict__ WTqkv,
    float* __restrict__ W1T, float* __restrict__ W2T) {
  int i = blockIdx.x * 256 + threadIdx.x;
  if (i < 256 * 320) {
    int k = i / 320, r = i % 320;
    float v;
    if (r < 32)      v = Wq[r * 256 + k];
    else if (r < 64) v = Wk[(r - 32) * 256 + k];
    else             v = Wv[(r - 64) * 256 + k];
    WTqkv[i] = v;
  }
  if (i < 256 * 1024) {
    int k = i >> 10, f = i & 1023;
    W1T[i] = W1[f * 256 + k];
  }
  if (i < 1024 * 256) {
    int f = i >> 8, c = i & 255;
    W2T[i] = W2[c * 1024 + f];
  }
}

// ---------------- kernel 1: QKV projection ----------------
// Q [32][M] fp32, K [32][M] fp32, V [256][M] bf16
__global__ __launch_bounds__(256) void qkv_kernel(
    const float* __restrict__ x, const float* __restrict__ WT,
    float* __restrict__ Q, float* __restrict__ K, bf16* __restrict__ V) {
  __shared__ float xs[256][32];
  const size_t colbase = (size_t)blockIdx.x * 32;
  const size_t b = colbase / HW_DIM;
  const size_t hw0 = colbase % HW_DIM;
  const float* xb = x + b * (size_t)C_DIM * HW_DIM + hw0;
  for (int idx = threadIdx.x; idx < 256 * 8; idx += 256) {
    int c = idx >> 3, p4 = idx & 7;
    *(float4*)&xs[c][p4 * 4] = *(const float4*)(xb + (size_t)c * HW_DIM + p4 * 4);
  }
  __syncthreads();
  const int r_local = threadIdx.x & 63;
  const int pg = threadIdx.x >> 6;   // 4 groups of 8 pixels
  for (int rc = 0; rc < 5; ++rc) {
    const int r = rc * 64 + r_local;
    float acc[8] = {0.f,0.f,0.f,0.f,0.f,0.f,0.f,0.f};
    #pragma unroll 4
    for (int k = 0; k < 256; ++k) {
      float w = WT[k * 320 + r];
      float4 a0 = *(float4*)&xs[k][pg * 8];
      float4 a1 = *(float4*)&xs[k][pg * 8 + 4];
      acc[0] = fmaf(w, a0.x, acc[0]);
      acc[1] = fmaf(w, a0.y, acc[1]);
      acc[2] = fmaf(w, a0.z, acc[2]);
      acc[3] = fmaf(w, a0.w, acc[3]);
      acc[4] = fmaf(w, a1.x, acc[4]);
      acc[5] = fmaf(w, a1.y, acc[5]);
      acc[6] = fmaf(w, a1.z, acc[6]);
      acc[7] = fmaf(w, a1.w, acc[7]);
    }
    size_t col = colbase + pg * 8;
    if (r < 32) {
      float* dst = Q + (size_t)r * M_TOT + col;
      *(float4*)dst = make_float4(acc[0], acc[1], acc[2], acc[3]);
      *(float4*)(dst + 4) = make_float4(acc[4], acc[5], acc[6], acc[7]);
    } else if (r < 64) {
      float* dst = K + (size_t)(r - 32) * M_TOT + col;
      *(float4*)dst = make_float4(acc[0], acc[1], acc[2], acc[3]);
      *(float4*)(dst + 4) = make_float4(acc[4], acc[5], acc[6], acc[7]);
    } else {
      bf16 hb[8];
      #pragma unroll
      for (int j = 0; j < 8; ++j) hb[j] = f2bf(acc[j]);
      *(float4*)(V + (size_t)(r - 64) * M_TOT + col) = *(float4*)hb;
    }
  }
}

// ---------------- kernel 2: per-window QK^T + softmax (unnormalized) ----------------
// A [512][256 n][256 m] bf16 = exp(s);  L [512][256] fp32 = row sums
__global__ __launch_bounds__(256) void attn_softmax_kernel(
    const float* __restrict__ Q, const float* __restrict__ K,
    bf16* __restrict__ A, float* __restrict__ L) {
  __shared__ float Kst[256][36];
  const int widx = blockIdx.x;
  const int b = widx >> 6, wh = (widx >> 3) & 7, ww = widx & 7;
  const size_t colbase = (size_t)b * HW_DIM + wh * 2048 + ww * 16;
  const int n = threadIdx.x;
  const size_t coln = colbase + (n >> 4) * 128 + (n & 15);
  float q[32];
  #pragma unroll
  for (int o = 0; o < 32; ++o) {
    q[o] = Q[(size_t)o * M_TOT + coln];
    Kst[n][o] = K[(size_t)o * M_TOT + coln];
  }
  __syncthreads();
  float l = 0.f;
  bf16* Arow = A + (size_t)widx * 65536 + (size_t)n * 256;
  for (int m8 = 0; m8 < 32; ++m8) {
    bf16 hb[8];
    #pragma unroll
    for (int mi = 0; mi < 8; ++mi) {
      int m = m8 * 8 + mi;
      float s = 0.f;
      #pragma unroll
      for (int o4 = 0; o4 < 8; ++o4) {
        float4 k4 = *(float4*)&Kst[m][o4 * 4];
        s = fmaf(q[o4 * 4 + 0], k4.x, s);
        s = fmaf(q[o4 * 4 + 1], k4.y, s);
        s = fmaf(q[o4 * 4 + 2], k4.z, s);
        s = fmaf(q[o4 * 4 + 3], k4.w, s);
      }
      hb[mi] = f2bf(__expf(s));
      l += bf2f(hb[mi]);
    }
    *(float4*)(Arow + m8 * 8) = *(float4*)hb;
  }
  L[(size_t)widx * 256 + n] = l;
}

// ---------------- kernel 3: out = gamma * (V @ A^T)/l + x  -> XA (= d_out) ----------------
__global__ __launch_bounds__(256) void attn_pv_kernel(
    const bf16* __restrict__ V, const bf16* __restrict__ A,
    const float* __restrict__ L, const float* __restrict__ x,
    const float* __restrict__ gamma, float* __restrict__ XA) {
  __shared__ float Vt[64][36];
  __shared__ float At[256][36];
  __shared__ float ls[256];
  const int widx = blockIdx.x >> 2;
  const int cg = blockIdx.x & 3;
  const int b = widx >> 6, wh = (widx >> 3) & 7, ww = widx & 7;
  const size_t colbase = (size_t)b * HW_DIM + wh * 2048 + ww * 16;
  const int tid = threadIdx.x;
  const int c_l = tid & 63, n16 = tid >> 6;
  ls[tid] = L[(size_t)widx * 256 + tid];
  float acc[64];
  #pragma unroll
  for (int j = 0; j < 64; ++j) acc[j] = 0.f;
  const unsigned int* Aw = (const unsigned int*)(A + (size_t)widx * 65536);
  const unsigned int* Vw = (const unsigned int*)V;
  for (int mc = 0; mc < 8; ++mc) {
    __syncthreads();
    // Vt: 64 c x 32 m (bf16 pairs)
    for (int idx = tid; idx < 64 * 16; idx += 256) {
      int c = idx >> 4, mp = idx & 15;
      int mt = mc * 32 + mp * 2;
      size_t col = colbase + (mt >> 4) * 128 + (mt & 15);
      unsigned int u = Vw[((size_t)(cg * 64 + c) * M_TOT + col) >> 1];
      Vt[c][mp * 2]     = __uint_as_float(u << 16);
      Vt[c][mp * 2 + 1] = __uint_as_float(u & 0xffff0000u);
    }
    // At: 256 n x 32 m
    for (int idx = tid; idx < 256 * 16; idx += 256) {
      int nn = idx >> 4, mp = idx & 15;
      unsigned int u = Aw[(size_t)nn * 128 + mc * 16 + mp];
      At[nn][mp * 2]     = __uint_as_float(u << 16);
      At[nn][mp * 2 + 1] = __uint_as_float(u & 0xffff0000u);
    }
    __syncthreads();
    #pragma unroll
    for (int m4 = 0; m4 < 8; ++m4) {
      float4 v4 = *(float4*)&Vt[c_l][m4 * 4];
      #pragma unroll 16
      for (int j = 0; j < 64; ++j) {
        float4 a4 = *(float4*)&At[n16 * 64 + j][m4 * 4];
        acc[j] = fmaf(v4.x, a4.x, acc[j]);
        acc[j] = fmaf(v4.y, a4.y, acc[j]);
        acc[j] = fmaf(v4.z, a4.z, acc[j]);
        acc[j] = fmaf(v4.w, a4.w, acc[j]);
      }
    }
  }
  const float g = gamma[0];
  const int c = cg * 64 + c_l;
  const size_t rowoff = (size_t)b * C_DIM * HW_DIM + (size_t)c * HW_DIM + wh * 2048 + ww * 16;
  const float* xrow = x + rowoff;
  float* orow = XA + rowoff;
  #pragma unroll
  for (int j4 = 0; j4 < 16; ++j4) {
    int j = j4 * 4;
    int nn = n16 * 64 + j;
    int gh = nn >> 4, gw = nn & 15;
    float4 xr = *(const float4*)(xrow + gh * 128 + gw);
    float4 o;
    o.x = g * acc[j + 0] / ls[nn + 0] + xr.x;
    o.y = g * acc[j + 1] / ls[nn + 1] + xr.y;
    o.z = g * acc[j + 2] / ls[nn + 2] + xr.z;
    o.w = g * acc[j + 3] / ls[nn + 3] + xr.w;
    *(float4*)(orow + gh * 128 + gw) = o;
  }
}

// ---------------- kernel 4: fused FFN + both LayerNorms (in-place on d_out) ----------------
__global__ __launch_bounds__(256) void ffn_kernel(
    float* __restrict__ XA,
    const float* __restrict__ W1T, const float* __restrict__ b1,
    const float* __restrict__ W2T, const float* __restrict__ b2,
    const float* __restrict__ ln1w, const float* __restrict__ ln1b,
    const float* __restrict__ ln2w, const float* __restrict__ ln2b) {
  __shared__ float xs[256][32];
  __shared__ float h1c[128][32];
  __shared__ float red[2][4][32];
  __shared__ float mu1[32], rs1[32], mu2[32], rs2[32];
  const size_t colbase = (size_t)blockIdx.x * 32;
  const size_t b = colbase / HW_DIM;
  const size_t hw0 = colbase % HW_DIM;
  float* xb = XA + b * (size_t)C_DIM * HW_DIM + hw0;
  const int tid = threadIdx.x;
  for (int idx = tid; idx < 256 * 8; idx += 256) {
    int c = idx >> 3, p4 = idx & 7;
    *(float4*)&xs[c][p4 * 4] = *(const float4*)(xb + (size_t)c * HW_DIM + p4 * 4);
  }
  __syncthreads();
  const int f_l = tid & 127, ph = tid >> 7;
  float y[32];
  #pragma unroll
  for (int p = 0; p < 32; ++p) y[p] = 0.f;
  for (int fc = 0; fc < 8; ++fc) {
    const int f = fc * 128 + f_l;
    float acc1[16];
    #pragma unroll
    for (int i = 0; i < 16; ++i) acc1[i] = 0.f;
    const float* w1p = W1T + f;
    #pragma unroll 2
    for (int k = 0; k < 256; ++k) {
      float w = w1p[k * 1024];
      #pragma unroll
      for (int p4 = 0; p4 < 4; ++p4) {
        float4 a = *(float4*)&xs[k][ph * 16 + p4 * 4];
        acc1[p4 * 4 + 0] = fmaf(w, a.x, acc1[p4 * 4 + 0]);
        acc1[p4 * 4 + 1] = fmaf(w, a.y, acc1[p4 * 4 + 1]);
        acc1[p4 * 4 + 2] = fmaf(w, a.z, acc1[p4 * 4 + 2]);
        acc1[p4 * 4 + 3] = fmaf(w, a.w, acc1[p4 * 4 + 3]);
      }
    }
    float bv = b1[f];
    __syncthreads();   // previous GEMM2 reads of h1c are done
    #pragma unroll
    for (int i = 0; i < 16; ++i) {
      float v = acc1[i] + bv;
      h1c[f_l][ph * 16 + i] = 0.5f * v * (1.f + erff(v * 0.70710678118f));
    }
    __syncthreads();
    const float* w2p = W2T + (size_t)(fc * 128) * 256 + tid;
    for (int ff = 0; ff < 128; ++ff) {
      float w2 = w2p[ff * 256];
      #pragma unroll
      for (int p4 = 0; p4 < 8; ++p4) {
        float4 h4 = *(float4*)&h1c[ff][p4 * 4];
        y[p4 * 4 + 0] = fmaf(w2, h4.x, y[p4 * 4 + 0]);
        y[p4 * 4 + 1] = fmaf(w2, h4.y, y[p4 * 4 + 1]);
        y[p4 * 4 + 2] = fmaf(w2, h4.z, y[p4 * 4 + 2]);
        y[p4 * 4 + 3] = fmaf(w2, h4.w, y[p4 * 4 + 3]);
      }
    }
  }
  {
    float bv2 = b2[tid];
    #pragma unroll
    for (int p = 0; p < 32; ++p) y[p] += bv2;
  }
  const int wv = tid >> 6, lane = tid & 63;
  // LN1 stats over channels (cross-thread)
  #pragma unroll
  for (int p = 0; p < 32; ++p) {
    float s = y[p], q = y[p] * y[p];
    #pragma unroll
    for (int off = 32; off > 0; off >>= 1) {
      s += __shfl_down(s, off);
      q += __shfl_down(q, off);
    }
    if (lane == 0) { red[0][wv][p] = s; red[1][wv][p] = q; }
  }
  __syncthreads();
  if (tid < 32) {
    float s = red[0][0][tid] + red[0][1][tid] + red[0][2][tid] + red[0][3][tid];
    float q = red[1][0][tid] + red[1][1][tid] + red[1][2][tid] + red[1][3][tid];
    float m = s * (1.f / 256.f);
    float v = q * (1.f / 256.f) - m * m;
    mu1[tid] = m;
    rs1[tid] = rsqrtf(v + 1e-5f);
  }
  __syncthreads();
  const float w1c = ln1w[tid], b1c = ln1b[tid];
  float x2[32];
  #pragma unroll
  for (int p = 0; p < 32; ++p)
    x2[p] = xs[tid][p] + (y[p] - mu1[p]) * rs1[p] * w1c + b1c;
  // LN2 stats
  #pragma unroll
  for (int p = 0; p < 32; ++p) {
    float s = x2[p], q = x2[p] * x2[p];
    #pragma unroll
    for (int off = 32; off > 0; off >>= 1) {
      s += __shfl_down(s, off);
      q += __shfl_down(q, off);
    }
    if (lane == 0) { red[0][wv][p] = s; red[1][wv][p] = q; }
  }
  __syncthreads();
  if (tid < 32) {
    float s = red[0][0][tid] + red[0][1][tid] + red[0][2][tid] + red[0][3][tid];
    float q = red[1][0][tid] + red[1][1][tid] + red[1][2][tid] + red[1][3][tid];
    float m = s * (1.f / 256.f);
    float v = q * (1.f / 256.f) - m * m;
    mu2[tid] = m;
    rs2[tid] = rsqrtf(v + 1e-5f);
  }
  __syncthreads();
  const float w2c = ln2w[tid], b2c = ln2b[tid];
  #pragma unroll
  for (int p4 = 0; p4 < 8; ++p4) {
    float4 o;
    float v0 = x2[p4 * 4 + 0], v1 = x2[p4 * 4 + 1], v2 = x2[p4 * 4 + 2], v3 = x2[p4 * 4 + 3];
    o.x = v0 + (v0 - mu2[p4 * 4 + 0]) * rs2[p4 * 4 + 0] * w2c + b2c;
    o.y = v1 + (v1 - mu2[p4 * 4 + 1]) * rs2[p4 * 4 + 1] * w2c + b2c;
    o.z = v2 + (v2 - mu2[p4 * 4 + 2]) * rs2[p4 * 4 + 2] * w2c + b2c;
    o.w = v3 + (v3 - mu2[p4 * 4 + 3]) * rs2[p4 * 4 + 3] * w2c + b2c;
    *(float4*)(xb + (size_t)tid * HW_DIM + p4 * 4) = o;
  }
}

extern "C" void kernel_launch(void* const* d_in, const int* in_sizes, int n_in,
                              void* d_out, int out_size, void* d_ws, size_t ws_size,
                              hipStream_t stream) {
  const float* x     = (const float*)d_in[0];
  const float* Wq    = (const float*)d_in[1];
  const float* Wk    = (const float*)d_in[2];
  const float* Wv    = (const float*)d_in[3];
  const float* gamma = (const float*)d_in[4];
  const float* W1    = (const float*)d_in[5];
  const float* b1    = (const float*)d_in[6];
  const float* W2    = (const float*)d_in[7];
  const float* b2    = (const float*)d_in[8];
  const float* ln1w  = (const float*)d_in[9];
  const float* ln1b  = (const float*)d_in[10];
  const float* ln2w  = (const float*)d_in[11];
  const float* ln2b  = (const float*)d_in[12];
  float* out = (float*)d_out;

  float* ws    = (float*)d_ws;
  float* WTqkv = ws;                       // 81920
  float* W1T   = WTqkv + 81920;            // 262144
  float* W2T   = W1T + 262144;             // 262144
  float* Q     = W2T + 262144;             // 4194304
  float* Kb    = Q + 4194304;              // 4194304
  float* L     = Kb + 4194304;             // 131072
  bf16*  V     = (bf16*)(L + 131072);      // 33554432 bf16
  bf16*  A     = V + (size_t)33554432;     // 33554432 bf16

  prep_weights<<<1024, 256, 0, stream>>>(Wq, Wk, Wv, W1, W2, WTqkv, W1T, W2T);
  qkv_kernel<<<4096, 256, 0, stream>>>(x, WTqkv, Q, Kb, V);
  attn_softmax_kernel<<<512, 256, 0, stream>>>(Q, Kb, A, L);
  attn_pv_kernel<<<2048, 256, 0, stream>>>(V, A, L, x, gamma, out);
  ffn_kernel<<<4096, 256, 0, stream>>>(out, W1T, b1, W2T, b2, ln1w, ln1b, ln2w, ln2b);
}

// Round 2
// 3982.457 us; speedup vs baseline: 1.6476x; 1.6476x over previous
//
#include <hip/hip_runtime.h>
#include <hip/hip_bf16.h>

#define C_DIM 256
#define HW_DIM 16384
#define M_TOT 131072   // B*H*W = 8*128*128
#define F_DIM 1024

typedef __hip_bfloat16 bf16;
typedef short short8 __attribute__((ext_vector_type(8)));
typedef float f32x4 __attribute__((ext_vector_type(4)));

__device__ __forceinline__ float bf2f(bf16 v) { return __bfloat162float(v); }
__device__ __forceinline__ bf16 f2bf(float v) { return __float2bfloat16(v); }
__device__ __forceinline__ unsigned short f2bfbits(float v) {
  bf16 h = __float2bfloat16(v);
  return *(unsigned short*)&h;
}

// ---------------- kernel 0: weight prep ----------------
// WTqkv [256 k][320 r] fp32 for qkv kernel.
// W1s: bf16 A-fragments, [ft(64)][ks(8)][lane(64)][j(8)]:
//   value = W1[f = ft*16 + (lane&15)][k = ks*32 + (lane>>4)*8 + j]
// W2s: bf16 A-fragments, [ct(16)][gks(32)][lane(64)][j(8)]:
//   value = W2[c = ct*16 + (lane&15)][f = gks*32 + (lane>>4)*8 + j]
__global__ __launch_bounds__(256) void prep_weights(
    const float* __restrict__ Wq, const float* __restrict__ Wk,
    const float* __restrict__ Wv, const float* __restrict__ W1,
    const float* __restrict__ W2, float* __restrict__ WTqkv,
    unsigned short* __restrict__ W1s, unsigned short* __restrict__ W2s) {
  int i = blockIdx.x * 256 + threadIdx.x;
  if (i < 256 * 320) {
    int k = i / 320, r = i % 320;
    float v;
    if (r < 32)      v = Wq[r * 256 + k];
    else if (r < 64) v = Wk[(r - 32) * 256 + k];
    else             v = Wv[(r - 64) * 256 + k];
    WTqkv[i] = v;
  }
  if (i < 32768) {
    int ft = i >> 9, ks = (i >> 6) & 7, l = i & 63;
    int f = ft * 16 + (l & 15), kb = ks * 32 + (l >> 4) * 8;
    #pragma unroll
    for (int j = 0; j < 8; ++j)
      W1s[i * 8 + j] = f2bfbits(W1[f * 256 + kb + j]);
  }
  if (i < 32768) {
    int ct = i >> 11, gks = (i >> 6) & 31, l = i & 63;
    int c = ct * 16 + (l & 15), fb = gks * 32 + (l >> 4) * 8;
    #pragma unroll
    for (int j = 0; j < 8; ++j)
      W2s[i * 8 + j] = f2bfbits(W2[c * 1024 + fb + j]);
  }
}

// ---------------- kernel 1: QKV projection (unchanged) ----------------
__global__ __launch_bounds__(256) void qkv_kernel(
    const float* __restrict__ x, const float* __restrict__ WT,
    float* __restrict__ Q, float* __restrict__ K, bf16* __restrict__ V) {
  __shared__ float xs[256][32];
  const size_t colbase = (size_t)blockIdx.x * 32;
  const size_t b = colbase / HW_DIM;
  const size_t hw0 = colbase % HW_DIM;
  const float* xb = x + b * (size_t)C_DIM * HW_DIM + hw0;
  for (int idx = threadIdx.x; idx < 256 * 8; idx += 256) {
    int c = idx >> 3, p4 = idx & 7;
    *(float4*)&xs[c][p4 * 4] = *(const float4*)(xb + (size_t)c * HW_DIM + p4 * 4);
  }
  __syncthreads();
  const int r_local = threadIdx.x & 63;
  const int pg = threadIdx.x >> 6;
  for (int rc = 0; rc < 5; ++rc) {
    const int r = rc * 64 + r_local;
    float acc[8] = {0.f,0.f,0.f,0.f,0.f,0.f,0.f,0.f};
    #pragma unroll 4
    for (int k = 0; k < 256; ++k) {
      float w = WT[k * 320 + r];
      float4 a0 = *(float4*)&xs[k][pg * 8];
      float4 a1 = *(float4*)&xs[k][pg * 8 + 4];
      acc[0] = fmaf(w, a0.x, acc[0]);
      acc[1] = fmaf(w, a0.y, acc[1]);
      acc[2] = fmaf(w, a0.z, acc[2]);
      acc[3] = fmaf(w, a0.w, acc[3]);
      acc[4] = fmaf(w, a1.x, acc[4]);
      acc[5] = fmaf(w, a1.y, acc[5]);
      acc[6] = fmaf(w, a1.z, acc[6]);
      acc[7] = fmaf(w, a1.w, acc[7]);
    }
    size_t col = colbase + pg * 8;
    if (r < 32) {
      float* dst = Q + (size_t)r * M_TOT + col;
      *(float4*)dst = make_float4(acc[0], acc[1], acc[2], acc[3]);
      *(float4*)(dst + 4) = make_float4(acc[4], acc[5], acc[6], acc[7]);
    } else if (r < 64) {
      float* dst = K + (size_t)(r - 32) * M_TOT + col;
      *(float4*)dst = make_float4(acc[0], acc[1], acc[2], acc[3]);
      *(float4*)(dst + 4) = make_float4(acc[4], acc[5], acc[6], acc[7]);
    } else {
      bf16 hb[8];
      #pragma unroll
      for (int j = 0; j < 8; ++j) hb[j] = f2bf(acc[j]);
      *(float4*)(V + (size_t)(r - 64) * M_TOT + col) = *(float4*)hb;
    }
  }
}

// ---------------- kernel 2: per-window QK^T + softmax (unchanged) ----------------
__global__ __launch_bounds__(256) void attn_softmax_kernel(
    const float* __restrict__ Q, const float* __restrict__ K,
    bf16* __restrict__ A, float* __restrict__ L) {
  __shared__ float Kst[256][36];
  const int widx = blockIdx.x;
  const int b = widx >> 6, wh = (widx >> 3) & 7, ww = widx & 7;
  const size_t colbase = (size_t)b * HW_DIM + wh * 2048 + ww * 16;
  const int n = threadIdx.x;
  const size_t coln = colbase + (n >> 4) * 128 + (n & 15);
  float q[32];
  #pragma unroll
  for (int o = 0; o < 32; ++o) {
    q[o] = Q[(size_t)o * M_TOT + coln];
    Kst[n][o] = K[(size_t)o * M_TOT + coln];
  }
  __syncthreads();
  float l = 0.f;
  bf16* Arow = A + (size_t)widx * 65536 + (size_t)n * 256;
  for (int m8 = 0; m8 < 32; ++m8) {
    bf16 hb[8];
    #pragma unroll
    for (int mi = 0; mi < 8; ++mi) {
      int m = m8 * 8 + mi;
      float s = 0.f;
      #pragma unroll
      for (int o4 = 0; o4 < 8; ++o4) {
        float4 k4 = *(float4*)&Kst[m][o4 * 4];
        s = fmaf(q[o4 * 4 + 0], k4.x, s);
        s = fmaf(q[o4 * 4 + 1], k4.y, s);
        s = fmaf(q[o4 * 4 + 2], k4.z, s);
        s = fmaf(q[o4 * 4 + 3], k4.w, s);
      }
      hb[mi] = f2bf(__expf(s));
      l += bf2f(hb[mi]);
    }
    *(float4*)(Arow + m8 * 8) = *(float4*)hb;
  }
  L[(size_t)widx * 256 + n] = l;
}

// ---------------- kernel 3: out = gamma * (V @ A^T)/l + x (unchanged) ----------------
__global__ __launch_bounds__(256) void attn_pv_kernel(
    const bf16* __restrict__ V, const bf16* __restrict__ A,
    const float* __restrict__ L, const float* __restrict__ x,
    const float* __restrict__ gamma, float* __restrict__ XA) {
  __shared__ float Vt[64][36];
  __shared__ float At[256][36];
  __shared__ float ls[256];
  const int widx = blockIdx.x >> 2;
  const int cg = blockIdx.x & 3;
  const int b = widx >> 6, wh = (widx >> 3) & 7, ww = widx & 7;
  const size_t colbase = (size_t)b * HW_DIM + wh * 2048 + ww * 16;
  const int tid = threadIdx.x;
  const int c_l = tid & 63, n16 = tid >> 6;
  ls[tid] = L[(size_t)widx * 256 + tid];
  float acc[64];
  #pragma unroll
  for (int j = 0; j < 64; ++j) acc[j] = 0.f;
  const unsigned int* Aw = (const unsigned int*)(A + (size_t)widx * 65536);
  const unsigned int* Vw = (const unsigned int*)V;
  for (int mc = 0; mc < 8; ++mc) {
    __syncthreads();
    for (int idx = tid; idx < 64 * 16; idx += 256) {
      int c = idx >> 4, mp = idx & 15;
      int mt = mc * 32 + mp * 2;
      size_t col = colbase + (mt >> 4) * 128 + (mt & 15);
      unsigned int u = Vw[((size_t)(cg * 64 + c) * M_TOT + col) >> 1];
      Vt[c][mp * 2]     = __uint_as_float(u << 16);
      Vt[c][mp * 2 + 1] = __uint_as_float(u & 0xffff0000u);
    }
    for (int idx = tid; idx < 256 * 16; idx += 256) {
      int nn = idx >> 4, mp = idx & 15;
      unsigned int u = Aw[(size_t)nn * 128 + mc * 16 + mp];
      At[nn][mp * 2]     = __uint_as_float(u << 16);
      At[nn][mp * 2 + 1] = __uint_as_float(u & 0xffff0000u);
    }
    __syncthreads();
    #pragma unroll
    for (int m4 = 0; m4 < 8; ++m4) {
      float4 v4 = *(float4*)&Vt[c_l][m4 * 4];
      #pragma unroll 16
      for (int j = 0; j < 64; ++j) {
        float4 a4 = *(float4*)&At[n16 * 64 + j][m4 * 4];
        acc[j] = fmaf(v4.x, a4.x, acc[j]);
        acc[j] = fmaf(v4.y, a4.y, acc[j]);
        acc[j] = fmaf(v4.z, a4.z, acc[j]);
        acc[j] = fmaf(v4.w, a4.w, acc[j]);
      }
    }
  }
  const float g = gamma[0];
  const int c = cg * 64 + c_l;
  const size_t rowoff = (size_t)b * C_DIM * HW_DIM + (size_t)c * HW_DIM + wh * 2048 + ww * 16;
  const float* xrow = x + rowoff;
  float* orow = XA + rowoff;
  #pragma unroll
  for (int j4 = 0; j4 < 16; ++j4) {
    int j = j4 * 4;
    int nn = n16 * 64 + j;
    int gh = nn >> 4, gw = nn & 15;
    float4 xr = *(const float4*)(xrow + gh * 128 + gw);
    float4 o;
    o.x = g * acc[j + 0] / ls[nn + 0] + xr.x;
    o.y = g * acc[j + 1] / ls[nn + 1] + xr.y;
    o.z = g * acc[j + 2] / ls[nn + 2] + xr.z;
    o.w = g * acc[j + 3] / ls[nn + 3] + xr.w;
    *(float4*)(orow + gh * 128 + gw) = o;
  }
}

// ---------------- kernel 4: fused MFMA FFN + both LayerNorms (in-place on d_out) ----------------
// Block: 256 threads = 4 waves, 64 pixels. f processed in 8 chunks of 128.
// GEMM1: H[128f x 64px] = W1chunk[128x256] @ X[256x64]; GELU -> LDS bf16
// GEMM2: Y[256c x 64px] += W2chunk[256x128] @ H[128x64]
// Epilogue: +b2, LN1, +residual, LN2, write fp32.
__global__ __launch_bounds__(256) void ffn_mfma_kernel(
    float* __restrict__ XA,
    const unsigned short* __restrict__ W1s, const unsigned short* __restrict__ W2s,
    const float* __restrict__ b1, const float* __restrict__ b2,
    const float* __restrict__ ln1w, const float* __restrict__ ln1b,
    const float* __restrict__ ln2w, const float* __restrict__ ln2b) {
  __shared__ short Xt[64][264];     // [px][c], pad to 264 -> conflict-free b128 frags
  __shared__ short Ht[64][136];     // [px][f_local], pad to 136
  __shared__ float red[2][4][64];
  __shared__ float s_mu[64], s_rs[64];
  __shared__ float s_b1[1024];
  __shared__ float s_b2[256], s_l1w[256], s_l1b[256], s_l2w[256], s_l2b[256];

  const int tid = threadIdx.x;
  const int wv = tid >> 6, l = tid & 63;
  const int p = l & 15, q = l >> 4;
  const int colbase = blockIdx.x * 64;
  const int b = colbase >> 14;
  const int hw0 = colbase & 16383;
  float* XAb = XA + (size_t)b * C_DIM * HW_DIM + hw0;

  // stage params
  s_b2[tid] = b2[tid];
  s_l1w[tid] = ln1w[tid]; s_l1b[tid] = ln1b[tid];
  s_l2w[tid] = ln2w[tid]; s_l2b[tid] = ln2b[tid];
  #pragma unroll
  for (int j = 0; j < 4; ++j) s_b1[j * 256 + tid] = b1[j * 256 + tid];

  // stage X tile: Xt[px][c] bf16
  {
    const int px = tid & 63, g = tid >> 6;
    #pragma unroll
    for (int it = 0; it < 16; ++it) {
      int cb = it * 16 + g * 4;
      ushort4 u;
      u.x = f2bfbits(XAb[(size_t)(cb + 0) * HW_DIM + px]);
      u.y = f2bfbits(XAb[(size_t)(cb + 1) * HW_DIM + px]);
      u.z = f2bfbits(XAb[(size_t)(cb + 2) * HW_DIM + px]);
      u.w = f2bfbits(XAb[(size_t)(cb + 3) * HW_DIM + px]);
      *(ushort4*)&Xt[px][cb] = u;
    }
  }
  __syncthreads();

  f32x4 Yacc[4][4];
  #pragma unroll
  for (int i = 0; i < 4; ++i)
    #pragma unroll
    for (int pt = 0; pt < 4; ++pt)
      Yacc[i][pt] = (f32x4){0.f, 0.f, 0.f, 0.f};

  const short8* W1s8 = (const short8*)W1s;
  const short8* W2s8 = (const short8*)W2s;

  for (int fc = 0; fc < 8; ++fc) {
    // ---- GEMM1: this wave computes f-tiles ft = fc*8 + wv*2 + {0,1} ----
    f32x4 Hacc[2][4];
    #pragma unroll
    for (int i = 0; i < 2; ++i)
      #pragma unroll
      for (int pt = 0; pt < 4; ++pt)
        Hacc[i][pt] = (f32x4){0.f, 0.f, 0.f, 0.f};
    const int f0 = (fc * 8 + wv * 2) * 8;
    #pragma unroll
    for (int ks = 0; ks < 8; ++ks) {
      short8 a0 = W1s8[(f0 + ks) * 64 + l];
      short8 a1 = W1s8[(f0 + 8 + ks) * 64 + l];
      #pragma unroll
      for (int pt = 0; pt < 4; ++pt) {
        short8 bf = *(const short8*)&Xt[pt * 16 + p][ks * 32 + q * 8];
        Hacc[0][pt] = __builtin_amdgcn_mfma_f32_16x16x32_bf16(a0, bf, Hacc[0][pt], 0, 0, 0);
        Hacc[1][pt] = __builtin_amdgcn_mfma_f32_16x16x32_bf16(a1, bf, Hacc[1][pt], 0, 0, 0);
      }
    }
    __syncthreads();   // prev chunk's GEMM2 reads of Ht done
    // ---- bias + GELU(tanh) -> Ht bf16 ----
    #pragma unroll
    for (int i = 0; i < 2; ++i) {
      #pragma unroll
      for (int pt = 0; pt < 4; ++pt) {
        ushort4 hb;
        unsigned short* hp = (unsigned short*)&hb;
        #pragma unroll
        for (int r = 0; r < 4; ++r) {
          int fl = wv * 32 + i * 16 + q * 4 + r;
          float v = Hacc[i][pt][r] + s_b1[fc * 128 + fl];
          float u = 0.7978845608f * fmaf(0.044715f * v, v * v, v);
          float e = __expf(2.f * u);
          float g = v - v / (e + 1.f);   // v*0.5*(1+tanh(u)), overflow-safe
          hp[r] = f2bfbits(g);
        }
        *(ushort4*)&Ht[pt * 16 + p][wv * 32 + i * 16 + q * 4] = hb;
      }
    }
    __syncthreads();
    // ---- GEMM2: this wave computes c-tiles ct = wv*4 + {0..3} ----
    #pragma unroll
    for (int fs = 0; fs < 4; ++fs) {
      short8 av[4];
      #pragma unroll
      for (int i = 0; i < 4; ++i)
        av[i] = W2s8[((wv * 4 + i) * 32 + fc * 4 + fs) * 64 + l];
      #pragma unroll
      for (int pt = 0; pt < 4; ++pt) {
        short8 bf = *(const short8*)&Ht[pt * 16 + p][fs * 32 + q * 8];
        #pragma unroll
        for (int i = 0; i < 4; ++i)
          Yacc[i][pt] = __builtin_amdgcn_mfma_f32_16x16x32_bf16(av[i], bf, Yacc[i][pt], 0, 0, 0);
      }
    }
  }

  // ---- epilogue: +b2, LN1 stats ----
  #pragma unroll
  for (int i = 0; i < 4; ++i)
    #pragma unroll
    for (int pt = 0; pt < 4; ++pt)
      #pragma unroll
      for (int r = 0; r < 4; ++r)
        Yacc[i][pt][r] += s_b2[wv * 64 + i * 16 + q * 4 + r];

  #pragma unroll
  for (int pt = 0; pt < 4; ++pt) {
    float ss = 0.f, sq = 0.f;
    #pragma unroll
    for (int i = 0; i < 4; ++i)
      #pragma unroll
      for (int r = 0; r < 4; ++r) { float v = Yacc[i][pt][r]; ss += v; sq += v * v; }
    ss += __shfl_xor(ss, 16); sq += __shfl_xor(sq, 16);
    ss += __shfl_xor(ss, 32); sq += __shfl_xor(sq, 32);
    if (l < 16) { red[0][wv][pt * 16 + l] = ss; red[1][wv][pt * 16 + l] = sq; }
  }
  __syncthreads();
  if (tid < 64) {
    float S  = red[0][0][tid] + red[0][1][tid] + red[0][2][tid] + red[0][3][tid];
    float Q2 = red[1][0][tid] + red[1][1][tid] + red[1][2][tid] + red[1][3][tid];
    float m = S * 0.00390625f;
    float va = Q2 * 0.00390625f - m * m;
    s_mu[tid] = m; s_rs[tid] = rsqrtf(va + 1e-5f);
  }
  __syncthreads();
  // x2 = xa + LN1(y)
  #pragma unroll
  for (int i = 0; i < 4; ++i) {
    #pragma unroll
    for (int pt = 0; pt < 4; ++pt) {
      int px = pt * 16 + p;
      #pragma unroll
      for (int r = 0; r < 4; ++r) {
        int c = wv * 64 + i * 16 + q * 4 + r;
        float xa = XAb[(size_t)c * HW_DIM + px];
        Yacc[i][pt][r] = xa + (Yacc[i][pt][r] - s_mu[px]) * s_rs[px] * s_l1w[c] + s_l1b[c];
      }
    }
  }
  // LN2 stats
  #pragma unroll
  for (int pt = 0; pt < 4; ++pt) {
    float ss = 0.f, sq = 0.f;
    #pragma unroll
    for (int i = 0; i < 4; ++i)
      #pragma unroll
      for (int r = 0; r < 4; ++r) { float v = Yacc[i][pt][r]; ss += v; sq += v * v; }
    ss += __shfl_xor(ss, 16); sq += __shfl_xor(sq, 16);
    ss += __shfl_xor(ss, 32); sq += __shfl_xor(sq, 32);
    if (l < 16) { red[0][wv][pt * 16 + l] = ss; red[1][wv][pt * 16 + l] = sq; }
  }
  __syncthreads();
  if (tid < 64) {
    float S  = red[0][0][tid] + red[0][1][tid] + red[0][2][tid] + red[0][3][tid];
    float Q2 = red[1][0][tid] + red[1][1][tid] + red[1][2][tid] + red[1][3][tid];
    float m = S * 0.00390625f;
    float va = Q2 * 0.00390625f - m * m;
    s_mu[tid] = m; s_rs[tid] = rsqrtf(va + 1e-5f);
  }
  __syncthreads();
  // out = x2 + LN2(x2)
  #pragma unroll
  for (int i = 0; i < 4; ++i) {
    #pragma unroll
    for (int pt = 0; pt < 4; ++pt) {
      int px = pt * 16 + p;
      #pragma unroll
      for (int r = 0; r < 4; ++r) {
        int c = wv * 64 + i * 16 + q * 4 + r;
        float x2 = Yacc[i][pt][r];
        XAb[(size_t)c * HW_DIM + px] = x2 + (x2 - s_mu[px]) * s_rs[px] * s_l2w[c] + s_l2b[c];
      }
    }
  }
}

extern "C" void kernel_launch(void* const* d_in, const int* in_sizes, int n_in,
                              void* d_out, int out_size, void* d_ws, size_t ws_size,
                              hipStream_t stream) {
  const float* x     = (const float*)d_in[0];
  const float* Wq    = (const float*)d_in[1];
  const float* Wk    = (const float*)d_in[2];
  const float* Wv    = (const float*)d_in[3];
  const float* gamma = (const float*)d_in[4];
  const float* W1    = (const float*)d_in[5];
  const float* b1    = (const float*)d_in[6];
  const float* W2    = (const float*)d_in[7];
  const float* b2    = (const float*)d_in[8];
  const float* ln1w  = (const float*)d_in[9];
  const float* ln1b  = (const float*)d_in[10];
  const float* ln2w  = (const float*)d_in[11];
  const float* ln2b  = (const float*)d_in[12];
  float* out = (float*)d_out;

  float* ws    = (float*)d_ws;
  float* WTqkv = ws;                                   // 81920 f32
  unsigned short* W1s = (unsigned short*)(WTqkv + 81920);  // 262144 bf16
  unsigned short* W2s = W1s + 262144;                      // 262144 bf16
  float* Q     = (float*)(W2s + 262144);               // 4194304 f32
  float* Kb    = Q + 4194304;                          // 4194304 f32
  float* L     = Kb + 4194304;                         // 131072 f32
  bf16*  V     = (bf16*)(L + 131072);                  // 33554432 bf16
  bf16*  A     = V + (size_t)33554432;                 // 33554432 bf16

  prep_weights<<<1024, 256, 0, stream>>>(Wq, Wk, Wv, W1, W2, WTqkv, W1s, W2s);
  qkv_kernel<<<4096, 256, 0, stream>>>(x, WTqkv, Q, Kb, V);
  attn_softmax_kernel<<<512, 256, 0, stream>>>(Q, Kb, A, L);
  attn_pv_kernel<<<2048, 256, 0, stream>>>(V, A, L, x, gamma, out);
  ffn_mfma_kernel<<<2048, 256, 0, stream>>>(out, W1s, W2s, b1, b2, ln1w, ln1b, ln2w, ln2b);
}

// Round 3
// 995.075 us; speedup vs baseline: 6.5939x; 4.0022x over previous
//
#include <hip/hip_runtime.h>
#include <hip/hip_bf16.h>

#define C_DIM 256
#define HW_DIM 16384
#define F_DIM 1024

typedef __hip_bfloat16 bf16;
typedef short short8 __attribute__((ext_vector_type(8)));
typedef float f32x4 __attribute__((ext_vector_type(4)));

__device__ __forceinline__ float bf2f(unsigned short u) {
  unsigned int x = ((unsigned int)u) << 16;
  return __uint_as_float(x);
}
__device__ __forceinline__ unsigned short f2bfbits(float v) {
  bf16 h = __float2bfloat16(v);
  return *(unsigned short*)&h;
}

// ---------------- kernel 0: weight prep ----------------
// Wqkv bf16 [320 r][256 c]: rows 0-31 Wq, 32-63 Wk, 64-319 Wv (row-major).
// W1s: bf16 A-fragments [ft(64)][ks(8)][lane(64)][j(8)]:
//   = W1[f = ft*16 + (lane&15)][k = ks*32 + (lane>>4)*8 + j]
// W2s: bf16 A-fragments [ct(16)][gks(32)][lane(64)][j(8)]:
//   = W2[c = ct*16 + (lane&15)][f = gks*32 + (lane>>4)*8 + j]
__global__ __launch_bounds__(256) void prep_weights(
    const float* __restrict__ Wq, const float* __restrict__ Wk,
    const float* __restrict__ Wv, const float* __restrict__ W1,
    const float* __restrict__ W2, unsigned short* __restrict__ Wqkv,
    unsigned short* __restrict__ W1s, unsigned short* __restrict__ W2s) {
  int i = blockIdx.x * 256 + threadIdx.x;
  if (i < 320 * 256) {
    int r = i >> 8, c = i & 255;
    float v;
    if (r < 32)      v = Wq[r * 256 + c];
    else if (r < 64) v = Wk[(r - 32) * 256 + c];
    else             v = Wv[(r - 64) * 256 + c];
    Wqkv[i] = f2bfbits(v);
  }
  if (i < 32768) {
    int ft = i >> 9, ks = (i >> 6) & 7, l = i & 63;
    int f = ft * 16 + (l & 15), kb = ks * 32 + (l >> 4) * 8;
    #pragma unroll
    for (int j = 0; j < 8; ++j)
      W1s[i * 8 + j] = f2bfbits(W1[f * 256 + kb + j]);
  }
  if (i < 32768) {
    int ct = i >> 11, gks = (i >> 6) & 31, l = i & 63;
    int c = ct * 16 + (l & 15), fb = gks * 32 + (l >> 4) * 8;
    #pragma unroll
    for (int j = 0; j < 8; ++j)
      W2s[i * 8 + j] = f2bfbits(W2[c * 1024 + fb + j]);
  }
}

// ---------------- kernel 1: QKV projection (MFMA, window-major outputs) ----------------
// block = (win, mc): stage Xs[c 256][m 64] bf16; out rows r: 0-31 Q, 32-63 K, 64-319 V.
// Qw/Kw [win][token 256][32] bf16;  Vw [win][c 256][m 256] bf16.
__global__ __launch_bounds__(256) void qkvproj_kernel(
    const float* __restrict__ x, const unsigned short* __restrict__ Wqkv,
    unsigned short* __restrict__ Qw, unsigned short* __restrict__ Kw,
    unsigned short* __restrict__ Vw) {
  __shared__ __align__(16) short Xs[256][68];   // stride 136 B (8B-aligned writes, 2-way-max banks)
  const int bid = blockIdx.x;
  const int win = bid >> 2, mc = bid & 3;
  const int b = win >> 6, wh = (win >> 3) & 7, ww = win & 7;
  const int m0 = mc * 64;
  const int tid = threadIdx.x;
  const int wv = tid >> 6, l = tid & 63;
  const int t = l & 15, q = l >> 4;

  // stage: x[b][c][wh*16 + mc*4 + gh_l][ww*16 + 0..15] -> Xs[c][gh_l*16 + gw]
  #pragma unroll
  for (int rep = 0; rep < 4; ++rep) {
    int seg = rep * 256 + tid;
    int c = seg >> 2, gh_l = seg & 3;
    const float* xp = x + (((size_t)(b * 256 + c) * 128) + wh * 16 + mc * 4 + gh_l) * 128 + ww * 16;
    #pragma unroll
    for (int s = 0; s < 4; ++s) {
      float4 v = *(const float4*)(xp + s * 4);
      ushort4 u;
      u.x = f2bfbits(v.x); u.y = f2bfbits(v.y);
      u.z = f2bfbits(v.z); u.w = f2bfbits(v.w);
      *(ushort4*)&Xs[c][gh_l * 16 + s * 4] = u;
    }
  }
  __syncthreads();

  for (int mt = 0; mt < 4; ++mt) {
    // B-fragments for this m-tile: B[k=c][col=m]
    short8 Bf[8];
    #pragma unroll
    for (int ks = 0; ks < 8; ++ks) {
      short8 bb;
      #pragma unroll
      for (int j = 0; j < 8; ++j)
        bb[j] = Xs[ks * 32 + q * 8 + j][mt * 16 + t];
      Bf[ks] = bb;
    }
    #pragma unroll
    for (int rti = 0; rti < 5; ++rti) {
      const int rt = wv * 5 + rti;
      const int r0 = rt * 16;
      f32x4 acc = (f32x4){0.f, 0.f, 0.f, 0.f};
      #pragma unroll
      for (int ks = 0; ks < 8; ++ks) {
        short8 av = *(const short8*)(Wqkv + (size_t)(r0 + t) * 256 + ks * 32 + q * 8);
        acc = __builtin_amdgcn_mfma_f32_16x16x32_bf16(av, Bf[ks], acc, 0, 0, 0);
      }
      const int n = m0 + mt * 16 + t;   // token (C-layout col)
      if (rt < 4) {
        ushort4 u;
        u.x = f2bfbits(acc[0]); u.y = f2bfbits(acc[1]);
        u.z = f2bfbits(acc[2]); u.w = f2bfbits(acc[3]);
        unsigned short* dst = (rt < 2) ? Qw : Kw;
        int o0 = (rt & 1) * 16 + q * 4;
        *(ushort4*)(dst + ((size_t)win * 256 + n) * 32 + o0) = u;
      } else {
        #pragma unroll
        for (int r = 0; r < 4; ++r) {
          int c = r0 - 64 + q * 4 + r;
          Vw[((size_t)win * 256 + c) * 256 + n] = f2bfbits(acc[r]);
        }
      }
    }
  }
}

// ---------------- kernel 2: fused window attention ----------------
// 1 block/window, 1024 thr = 16 waves (wr=wid>>2, wc=wid&3).
// S = Q K^T -> exp -> Ps (LDS bf16 chunk) -> O += P V (V B-frags from global Vw).
// Epilogue: O' = (gamma/l[n]) * O + x (fp32), transpose via LDS, write XAw[win][c][m] bf16.
__global__ __launch_bounds__(1024) void attn_fused_kernel(
    const unsigned short* __restrict__ Qw, const unsigned short* __restrict__ Kw,
    const unsigned short* __restrict__ Vw, const float* __restrict__ x,
    const float* __restrict__ gamma, unsigned short* __restrict__ XAw) {
  __shared__ __align__(16) short Ps[256][72];  // 36864 B; reused as Tbuf[32][264] f32 (33792 B)
  __shared__ float Lpart[4][4][64];
  __shared__ float Ls[256];

  const int win = blockIdx.x;
  const int b = win >> 6, wh = (win >> 3) & 7, ww = win & 7;
  const int tid = threadIdx.x;
  const int wid = tid >> 6, l = tid & 63;
  const int t = l & 15, q = l >> 4;
  const int wr = wid >> 2, wc = wid & 3;

  f32x4 Oacc[4][4];
  #pragma unroll
  for (int i = 0; i < 4; ++i)
    #pragma unroll
    for (int k = 0; k < 4; ++k)
      Oacc[i][k] = (f32x4){0.f, 0.f, 0.f, 0.f};
  float lsum[16];
  #pragma unroll
  for (int e = 0; e < 16; ++e) lsum[e] = 0.f;

  const unsigned short* Qb = Qw + (size_t)win * 256 * 32;
  const unsigned short* Kb = Kw + (size_t)win * 256 * 32;
  const unsigned short* Vb = Vw + (size_t)win * 65536;

  for (int mcc = 0; mcc < 4; ++mcc) {
    // ---- S chunk: wave (wr,wc): tiles nt = wr*4+i, mt = mcc*4+wc ----
    {
      const int m0s = (mcc * 4 + wc) * 16;
      short8 bk = *(const short8*)(Kb + (size_t)(m0s + t) * 32 + q * 8);
      f32x4 sv[4];
      #pragma unroll
      for (int i = 0; i < 4; ++i) {
        const int n0 = (wr * 4 + i) * 16;
        short8 aq = *(const short8*)(Qb + (size_t)(n0 + t) * 32 + q * 8);
        sv[i] = __builtin_amdgcn_mfma_f32_16x16x32_bf16(aq, bk, (f32x4){0.f,0.f,0.f,0.f}, 0, 0, 0);
      }
      #pragma unroll
      for (int i = 0; i < 4; ++i) {
        #pragma unroll
        for (int r = 0; r < 4; ++r) {
          float e = __expf(sv[i][r]);
          lsum[i * 4 + r] += e;
          Ps[(wr * 4 + i) * 16 + q * 4 + r][wc * 16 + t] = (short)f2bfbits(e);
        }
      }
    }
    __syncthreads();
    // ---- PV chunk: O[nt][ct] += P[:, chunk] @ V[chunk, :] ----
    #pragma unroll
    for (int ks2 = 0; ks2 < 2; ++ks2) {
      short8 ap[4], bv[4];
      #pragma unroll
      for (int i = 0; i < 4; ++i)
        ap[i] = *(const short8*)&Ps[(wr * 4 + i) * 16 + t][ks2 * 32 + q * 8];
      #pragma unroll
      for (int k = 0; k < 4; ++k)
        bv[k] = *(const short8*)(Vb + (size_t)((wc * 4 + k) * 16 + t) * 256 + mcc * 64 + ks2 * 32 + q * 8);
      #pragma unroll
      for (int i = 0; i < 4; ++i)
        #pragma unroll
        for (int k = 0; k < 4; ++k)
          Oacc[i][k] = __builtin_amdgcn_mfma_f32_16x16x32_bf16(ap[i], bv[k], Oacc[i][k], 0, 0, 0);
    }
    __syncthreads();
  }

  // ---- row sums: reduce over the 16 col-lanes, combine across wc ----
  #pragma unroll
  for (int mask = 1; mask < 16; mask <<= 1)
    #pragma unroll
    for (int e = 0; e < 16; ++e)
      lsum[e] += __shfl_xor(lsum[e], mask);
  if (t == 0) {
    #pragma unroll
    for (int i = 0; i < 4; ++i)
      *(float4*)&Lpart[wr][wc][i * 16 + q * 4] =
          make_float4(lsum[i * 4 + 0], lsum[i * 4 + 1], lsum[i * 4 + 2], lsum[i * 4 + 3]);
  }
  __syncthreads();
  if (tid < 256) {
    int wrr = tid >> 6, nl = tid & 63;
    float s = Lpart[wrr][0][nl] + Lpart[wrr][1][nl] + Lpart[wrr][2][nl] + Lpart[wrr][3][nl];
    Ls[tid] = gamma[0] / s;
  }
  __syncthreads();

  // ---- epilogue: per 32-channel chunk, transpose via LDS, write XAw bf16 ----
  float* Tbuf = (float*)&Ps[0][0];    // [32][264]
  for (int cc = 0; cc < 8; ++cc) {
    if ((cc >> 1) == wc) {
      #pragma unroll
      for (int kk = 0; kk < 2; ++kk) {
        const int k = (cc & 1) * 2 + kk;
        const int c = (wc * 4 + k) * 16 + t;
        const int c_l = kk * 16 + t;
        #pragma unroll
        for (int i = 0; i < 4; ++i) {
          const int nt = wr * 4 + i;
          const int n0 = nt * 16 + q * 4;
          float4 ls4 = *(float4*)&Ls[n0];
          float4 xr = *(const float4*)(x + (((size_t)(b * 256 + c) * 128) + wh * 16 + nt) * 128 + ww * 16 + q * 4);
          float4 o;
          o.x = ls4.x * Oacc[i][k][0] + xr.x;
          o.y = ls4.y * Oacc[i][k][1] + xr.y;
          o.z = ls4.z * Oacc[i][k][2] + xr.z;
          o.w = ls4.w * Oacc[i][k][3] + xr.w;
          *(float4*)&Tbuf[c_l * 264 + n0] = o;
        }
      }
    }
    __syncthreads();
    {
      const int c_l = tid >> 5, ms = (tid & 31) * 8;
      float4 v0 = *(float4*)&Tbuf[c_l * 264 + ms];
      float4 v1 = *(float4*)&Tbuf[c_l * 264 + ms + 4];
      ushort4 h0, h1;
      h0.x = f2bfbits(v0.x); h0.y = f2bfbits(v0.y); h0.z = f2bfbits(v0.z); h0.w = f2bfbits(v0.w);
      h1.x = f2bfbits(v1.x); h1.y = f2bfbits(v1.y); h1.z = f2bfbits(v1.z); h1.w = f2bfbits(v1.w);
      unsigned short* dst = XAw + ((size_t)win * 256 + cc * 32 + c_l) * 256 + ms;
      *(ushort4*)dst = h0;
      *(ushort4*)(dst + 4) = h1;
    }
    __syncthreads();
  }
}

// ---------------- kernel 3: fused MFMA FFN + both LayerNorms ----------------
// block = (win, mc): 64 pixels = window m-chunk. Reads XAw[win][c][m] bf16, writes d_out NCHW fp32.
__global__ __launch_bounds__(256) void ffn_mfma_kernel(
    const unsigned short* __restrict__ XAw,
    const unsigned short* __restrict__ W1s, const unsigned short* __restrict__ W2s,
    const float* __restrict__ b1, const float* __restrict__ b2,
    const float* __restrict__ ln1w, const float* __restrict__ ln1b,
    const float* __restrict__ ln2w, const float* __restrict__ ln2b,
    float* __restrict__ out) {
  __shared__ __align__(16) short Xt[64][264];
  __shared__ __align__(16) short Ht[64][136];
  __shared__ float red[2][4][64];
  __shared__ float s_mu[64], s_rs[64];
  __shared__ float s_b1[1024];
  __shared__ float s_b2[256], s_l1w[256], s_l1b[256], s_l2w[256], s_l2b[256];

  const int bid = blockIdx.x;
  const int win = bid >> 2, mc = bid & 3;
  const int b = win >> 6, wh = (win >> 3) & 7, ww = win & 7;
  const int tid = threadIdx.x;
  const int wv = tid >> 6, l = tid & 63;
  const int p = l & 15, q = l >> 4;
  const unsigned short* XWb = XAw + (size_t)win * 65536 + mc * 64;

  s_b2[tid] = b2[tid];
  s_l1w[tid] = ln1w[tid]; s_l1b[tid] = ln1b[tid];
  s_l2w[tid] = ln2w[tid]; s_l2b[tid] = ln2b[tid];
  #pragma unroll
  for (int j = 0; j < 4; ++j) s_b1[j * 256 + tid] = b1[j * 256 + tid];

  // stage X tile: Xt[px][c] bf16 from XAw[c][m0+px]
  #pragma unroll
  for (int rep = 0; rep < 16; ++rep) {
    int idx = rep * 256 + tid;
    int c = idx >> 4, m4 = (idx & 15) * 4;
    ushort4 u = *(const ushort4*)(XWb + (size_t)c * 256 + m4);
    Xt[m4 + 0][c] = (short)u.x;
    Xt[m4 + 1][c] = (short)u.y;
    Xt[m4 + 2][c] = (short)u.z;
    Xt[m4 + 3][c] = (short)u.w;
  }
  __syncthreads();

  f32x4 Yacc[4][4];
  #pragma unroll
  for (int i = 0; i < 4; ++i)
    #pragma unroll
    for (int pt = 0; pt < 4; ++pt)
      Yacc[i][pt] = (f32x4){0.f, 0.f, 0.f, 0.f};

  const short8* W1s8 = (const short8*)W1s;
  const short8* W2s8 = (const short8*)W2s;

  for (int fc = 0; fc < 8; ++fc) {
    f32x4 Hacc[2][4];
    #pragma unroll
    for (int i = 0; i < 2; ++i)
      #pragma unroll
      for (int pt = 0; pt < 4; ++pt)
        Hacc[i][pt] = (f32x4){0.f, 0.f, 0.f, 0.f};
    const int f0 = (fc * 8 + wv * 2) * 8;
    #pragma unroll
    for (int ks = 0; ks < 8; ++ks) {
      short8 a0 = W1s8[(f0 + ks) * 64 + l];
      short8 a1 = W1s8[(f0 + 8 + ks) * 64 + l];
      #pragma unroll
      for (int pt = 0; pt < 4; ++pt) {
        short8 bf = *(const short8*)&Xt[pt * 16 + p][ks * 32 + q * 8];
        Hacc[0][pt] = __builtin_amdgcn_mfma_f32_16x16x32_bf16(a0, bf, Hacc[0][pt], 0, 0, 0);
        Hacc[1][pt] = __builtin_amdgcn_mfma_f32_16x16x32_bf16(a1, bf, Hacc[1][pt], 0, 0, 0);
      }
    }
    __syncthreads();
    #pragma unroll
    for (int i = 0; i < 2; ++i) {
      #pragma unroll
      for (int pt = 0; pt < 4; ++pt) {
        ushort4 hb;
        unsigned short* hp = (unsigned short*)&hb;
        #pragma unroll
        for (int r = 0; r < 4; ++r) {
          int fl = wv * 32 + i * 16 + q * 4 + r;
          float v = Hacc[i][pt][r] + s_b1[fc * 128 + fl];
          float u = 0.7978845608f * fmaf(0.044715f * v, v * v, v);
          float e = __expf(2.f * u);
          float g = v - v / (e + 1.f);
          hp[r] = f2bfbits(g);
        }
        *(ushort4*)&Ht[pt * 16 + p][wv * 32 + i * 16 + q * 4] = hb;
      }
    }
    __syncthreads();
    #pragma unroll
    for (int fs = 0; fs < 4; ++fs) {
      short8 av[4];
      #pragma unroll
      for (int i = 0; i < 4; ++i)
        av[i] = W2s8[((wv * 4 + i) * 32 + fc * 4 + fs) * 64 + l];
      #pragma unroll
      for (int pt = 0; pt < 4; ++pt) {
        short8 bf = *(const short8*)&Ht[pt * 16 + p][fs * 32 + q * 8];
        #pragma unroll
        for (int i = 0; i < 4; ++i)
          Yacc[i][pt] = __builtin_amdgcn_mfma_f32_16x16x32_bf16(av[i], bf, Yacc[i][pt], 0, 0, 0);
      }
    }
  }

  #pragma unroll
  for (int i = 0; i < 4; ++i)
    #pragma unroll
    for (int pt = 0; pt < 4; ++pt)
      #pragma unroll
      for (int r = 0; r < 4; ++r)
        Yacc[i][pt][r] += s_b2[wv * 64 + i * 16 + q * 4 + r];

  #pragma unroll
  for (int pt = 0; pt < 4; ++pt) {
    float ss = 0.f, sq = 0.f;
    #pragma unroll
    for (int i = 0; i < 4; ++i)
      #pragma unroll
      for (int r = 0; r < 4; ++r) { float v = Yacc[i][pt][r]; ss += v; sq += v * v; }
    ss += __shfl_xor(ss, 16); sq += __shfl_xor(sq, 16);
    ss += __shfl_xor(ss, 32); sq += __shfl_xor(sq, 32);
    if (l < 16) { red[0][wv][pt * 16 + l] = ss; red[1][wv][pt * 16 + l] = sq; }
  }
  __syncthreads();
  if (tid < 64) {
    float S  = red[0][0][tid] + red[0][1][tid] + red[0][2][tid] + red[0][3][tid];
    float Q2 = red[1][0][tid] + red[1][1][tid] + red[1][2][tid] + red[1][3][tid];
    float m = S * 0.00390625f;
    float va = Q2 * 0.00390625f - m * m;
    s_mu[tid] = m; s_rs[tid] = rsqrtf(va + 1e-5f);
  }
  __syncthreads();
  // x2 = xa + LN1(y)
  #pragma unroll
  for (int i = 0; i < 4; ++i) {
    #pragma unroll
    for (int pt = 0; pt < 4; ++pt) {
      int px = pt * 16 + p;
      #pragma unroll
      for (int r = 0; r < 4; ++r) {
        int c = wv * 64 + i * 16 + q * 4 + r;
        float xa = bf2f(XWb[(size_t)c * 256 + px]);
        Yacc[i][pt][r] = xa + (Yacc[i][pt][r] - s_mu[px]) * s_rs[px] * s_l1w[c] + s_l1b[c];
      }
    }
  }
  #pragma unroll
  for (int pt = 0; pt < 4; ++pt) {
    float ss = 0.f, sq = 0.f;
    #pragma unroll
    for (int i = 0; i < 4; ++i)
      #pragma unroll
      for (int r = 0; r < 4; ++r) { float v = Yacc[i][pt][r]; ss += v; sq += v * v; }
    ss += __shfl_xor(ss, 16); sq += __shfl_xor(sq, 16);
    ss += __shfl_xor(ss, 32); sq += __shfl_xor(sq, 32);
    if (l < 16) { red[0][wv][pt * 16 + l] = ss; red[1][wv][pt * 16 + l] = sq; }
  }
  __syncthreads();
  if (tid < 64) {
    float S  = red[0][0][tid] + red[0][1][tid] + red[0][2][tid] + red[0][3][tid];
    float Q2 = red[1][0][tid] + red[1][1][tid] + red[1][2][tid] + red[1][3][tid];
    float m = S * 0.00390625f;
    float va = Q2 * 0.00390625f - m * m;
    s_mu[tid] = m; s_rs[tid] = rsqrtf(va + 1e-5f);
  }
  __syncthreads();
  // out = x2 + LN2(x2), NCHW
  #pragma unroll
  for (int i = 0; i < 4; ++i) {
    #pragma unroll
    for (int pt = 0; pt < 4; ++pt) {
      int px = pt * 16 + p;
      #pragma unroll
      for (int r = 0; r < 4; ++r) {
        int c = wv * 64 + i * 16 + q * 4 + r;
        float x2 = Yacc[i][pt][r];
        float o = x2 + (x2 - s_mu[px]) * s_rs[px] * s_l2w[c] + s_l2b[c];
        out[(((size_t)(b * 256 + c) * 128) + wh * 16 + mc * 4 + pt) * 128 + ww * 16 + p] = o;
      }
    }
  }
}

extern "C" void kernel_launch(void* const* d_in, const int* in_sizes, int n_in,
                              void* d_out, int out_size, void* d_ws, size_t ws_size,
                              hipStream_t stream) {
  const float* x     = (const float*)d_in[0];
  const float* Wq    = (const float*)d_in[1];
  const float* Wk    = (const float*)d_in[2];
  const float* Wv    = (const float*)d_in[3];
  const float* gamma = (const float*)d_in[4];
  const float* W1    = (const float*)d_in[5];
  const float* b1    = (const float*)d_in[6];
  const float* W2    = (const float*)d_in[7];
  const float* b2    = (const float*)d_in[8];
  const float* ln1w  = (const float*)d_in[9];
  const float* ln1b  = (const float*)d_in[10];
  const float* ln2w  = (const float*)d_in[11];
  const float* ln2b  = (const float*)d_in[12];
  float* out = (float*)d_out;

  char* wsb = (char*)d_ws;
  unsigned short* XAw  = (unsigned short*)wsb;                 // 33554432 bf16 = 67108864 B
  unsigned short* Vw   = (unsigned short*)(wsb + 67108864);    // 33554432 bf16
  unsigned short* Qw   = (unsigned short*)(wsb + 134217728);   // 4194304 bf16
  unsigned short* Kw   = (unsigned short*)(wsb + 142606336);   // 4194304 bf16
  unsigned short* Wqkv = (unsigned short*)(wsb + 150994944);   // 81920 bf16
  unsigned short* W1s  = (unsigned short*)(wsb + 151158784);   // 262144 bf16
  unsigned short* W2s  = (unsigned short*)(wsb + 151683072);   // 262144 bf16 -> end ~145 MB

  prep_weights<<<1024, 256, 0, stream>>>(Wq, Wk, Wv, W1, W2, Wqkv, W1s, W2s);
  qkvproj_kernel<<<2048, 256, 0, stream>>>(x, Wqkv, Qw, Kw, Vw);
  attn_fused_kernel<<<512, 1024, 0, stream>>>(Qw, Kw, Vw, x, gamma, XAw);
  ffn_mfma_kernel<<<2048, 256, 0, stream>>>(XAw, W1s, W2s, b1, b2, ln1w, ln1b, ln2w, ln2b, out);
}